// Round 2
// baseline (192.474 us; speedup 1.0000x reference)
//
#include <hip/hip_runtime.h>

// Problem constants (from reference)
#define B_ 32
#define S_ 512
#define H_ 768
#define C_ 32      // N_COLS
#define L_ 16      // MAX_HLEN

// One block per (b,s) token. 192 threads x 4 h-elems (float4) = 768 = H.
__global__ __launch_bounds__(192) void bert_emb_kernel(
    const int* __restrict__ input_ids,       // [B,S]
    const int* __restrict__ header_ids,      // [B,C,L]
    const int* __restrict__ token_type_ids,  // [B,S]
    const int* __restrict__ match_type_ids,  // [B,S]
    const int* __restrict__ type_idx,        // [B,S]
    const int* __restrict__ col_pos,         // [B,C]
    const int* __restrict__ col_idx,         // [B,C]
    const int* __restrict__ header_len,      // [B,C]
    const float* __restrict__ word_emb,      // [VOCAB,H] f32
    const float* __restrict__ pos_emb,       // [MAX_POS,H]
    const float* __restrict__ tok_type_emb,  // [2,H]
    const float* __restrict__ match_emb,     // [11,H]
    const float* __restrict__ type_emb,      // [6,H]
    const float* __restrict__ ln_w,          // [H]
    const float* __restrict__ ln_b,          // [H]
    float* __restrict__ out)                 // [B,S,H] f32
{
    const int bs = blockIdx.x;
    const int b  = bs >> 9;        // / S_
    const int s  = bs & (S_ - 1);
    const int t  = threadIdx.x;    // 0..191
    const int h0 = t << 2;         // 4*t

    // ---- block-uniform: does this token get an overridden (pooled) word vector?
    int ov = -1;
    #pragma unroll 8
    for (int c = 0; c < C_; ++c) {
        if (col_pos[b * C_ + c] == s) ov = c;
    }
    int use_pool = 0, ci = 0, hlen = 0;
    if (ov >= 0) {
        ci   = col_idx[b * C_ + ov];
        hlen = header_len[b * C_ + ci];
        if (hlen > 0) use_pool = 1;
    }

    // ---- word vector (either gather or variable-length mean pool)
    float ax, ay, az, aw;
    if (use_pool) {
        ax = ay = az = aw = 0.f;
        const int* hid = header_ids + (b * C_ + ci) * L_;
        for (int l = 0; l < hlen; ++l) {
            float4 v = *reinterpret_cast<const float4*>(
                word_emb + (size_t)hid[l] * H_ + h0);
            ax += v.x; ay += v.y; az += v.z; aw += v.w;
        }
        float inv = 1.0f / (float)hlen;
        ax *= inv; ay *= inv; az *= inv; aw *= inv;
    } else {
        float4 v = *reinterpret_cast<const float4*>(
            word_emb + (size_t)input_ids[bs] * H_ + h0);
        ax = v.x; ay = v.y; az = v.z; aw = v.w;
    }

    // ---- add the four auxiliary embeddings
    {
        float4 v = *reinterpret_cast<const float4*>(pos_emb + s * H_ + h0);
        ax += v.x; ay += v.y; az += v.z; aw += v.w;
    }
    {
        float4 v = *reinterpret_cast<const float4*>(
            tok_type_emb + token_type_ids[bs] * H_ + h0);
        ax += v.x; ay += v.y; az += v.z; aw += v.w;
    }
    {
        float4 v = *reinterpret_cast<const float4*>(
            match_emb + match_type_ids[bs] * H_ + h0);
        ax += v.x; ay += v.y; az += v.z; aw += v.w;
    }
    {
        float4 v = *reinterpret_cast<const float4*>(
            type_emb + type_idx[bs] * H_ + h0);
        ax += v.x; ay += v.y; az += v.z; aw += v.w;
    }

    // ---- LayerNorm over H=768: block reduction of sum and sumsq
    float s1 = ax + ay + az + aw;
    float s2 = ax * ax + ay * ay + az * az + aw * aw;
    #pragma unroll
    for (int off = 32; off > 0; off >>= 1) {
        s1 += __shfl_down(s1, off);
        s2 += __shfl_down(s2, off);
    }
    __shared__ float r1[3], r2[3];
    const int wv = t >> 6, ln = t & 63;
    if (ln == 0) { r1[wv] = s1; r2[wv] = s2; }
    __syncthreads();
    const float tot1 = r1[0] + r1[1] + r1[2];
    const float tot2 = r2[0] + r2[1] + r2[2];
    const float mean = tot1 * (1.0f / H_);
    float var = tot2 * (1.0f / H_) - mean * mean;
    var = fmaxf(var, 0.0f);
    const float rstd = rsqrtf(var + 1e-12f);

    // ---- scale/shift, store f32
    float4 w  = *reinterpret_cast<const float4*>(ln_w + h0);
    float4 bb = *reinterpret_cast<const float4*>(ln_b + h0);
    float4 o;
    o.x = (ax - mean) * rstd * w.x + bb.x;
    o.y = (ay - mean) * rstd * w.y + bb.y;
    o.z = (az - mean) * rstd * w.z + bb.z;
    o.w = (aw - mean) * rstd * w.w + bb.w;
    *reinterpret_cast<float4*>(out + (size_t)bs * H_ + h0) = o;
}

extern "C" void kernel_launch(void* const* d_in, const int* in_sizes, int n_in,
                              void* d_out, int out_size, void* d_ws, size_t ws_size,
                              hipStream_t stream) {
    const int* input_ids      = (const int*)d_in[0];
    const int* header_ids     = (const int*)d_in[1];
    const int* token_type_ids = (const int*)d_in[2];
    const int* match_type_ids = (const int*)d_in[3];
    const int* type_idx       = (const int*)d_in[4];
    const int* col_pos        = (const int*)d_in[5];
    const int* col_idx        = (const int*)d_in[6];
    const int* header_len     = (const int*)d_in[7];
    const float* word_emb     = (const float*)d_in[8];
    const float* pos_emb      = (const float*)d_in[9];
    const float* tok_type_emb = (const float*)d_in[10];
    const float* match_emb    = (const float*)d_in[11];
    const float* type_emb     = (const float*)d_in[12];
    const float* ln_w         = (const float*)d_in[13];
    const float* ln_b         = (const float*)d_in[14];
    float* out = (float*)d_out;

    bert_emb_kernel<<<B_ * S_, 192, 0, stream>>>(
        input_ids, header_ids, token_type_ids, match_type_ids, type_idx,
        col_pos, col_idx, header_len, word_emb, pos_emb, tok_type_emb,
        match_emb, type_emb, ln_w, ln_b, out);
}

// Round 3
// 191.182 us; speedup vs baseline: 1.0068x; 1.0068x over previous
//
#include <hip/hip_runtime.h>

// Problem constants (from reference)
#define B_ 32
#define S_ 512
#define H_ 768
#define C_ 32      // N_COLS
#define L_ 16      // MAX_HLEN

// One WAVE (64 lanes) per token; 12 floats per lane (3 x float4 chunks of 256).
// 256-thread blocks = 4 waves = 4 tokens per block -> grid = B*S/4 = 4096.
// No __syncthreads anywhere: LayerNorm reduce is a wave-level shfl_xor butterfly.
__global__ __launch_bounds__(256) void bert_emb_kernel(
    const int* __restrict__ input_ids,       // [B,S]
    const int* __restrict__ header_ids,      // [B,C,L]
    const int* __restrict__ token_type_ids,  // [B,S]
    const int* __restrict__ match_type_ids,  // [B,S]
    const int* __restrict__ type_idx,        // [B,S]
    const int* __restrict__ col_pos,         // [B,C]
    const int* __restrict__ col_idx,         // [B,C]
    const int* __restrict__ header_len,      // [B,C]
    const float* __restrict__ word_emb,      // [VOCAB,H] f32
    const float* __restrict__ pos_emb,       // [MAX_POS,H]
    const float* __restrict__ tok_type_emb,  // [2,H]
    const float* __restrict__ match_emb,     // [11,H]
    const float* __restrict__ type_emb,      // [6,H]
    const float* __restrict__ ln_w,          // [H]
    const float* __restrict__ ln_b,          // [H]
    float* __restrict__ out)                 // [B,S,H] f32
{
    const int tok  = blockIdx.x * 4 + (threadIdx.x >> 6);  // 0..16383
    const int lane = threadIdx.x & 63;
    const int b    = tok >> 9;        // / S_
    const int s    = tok & (S_ - 1);

    // ---- does this token get an overridden (pooled) word vector?
    // One ballot over 32 lanes replaces the 32-iteration scan.
    const int cq = lane & 31;
    const int cp = col_pos[(b << 5) + cq];
    unsigned long long m = __ballot(cp == s) & 0xffffffffULL;  // low 32 lanes only
    int use_pool = 0, ci = 0, hlen = 0;
    if (m) {
        const int cm = __ffsll((unsigned long long)m) - 1;     // col_pos distinct -> unique
        ci   = col_idx[(b << 5) + cm];
        hlen = header_len[(b << 5) + ci];
        use_pool = (hlen > 0);
    }

    // lane owns h = lane*4 + k*256, k = 0..2  (each chunk a coalesced 1 KiB load)
    const int h = lane << 2;
    float a0x, a0y, a0z, a0w, a1x, a1y, a1z, a1w, a2x, a2y, a2z, a2w;

    // ---- word vector (gather or variable-length mean pool)
    if (use_pool) {
        a0x=a0y=a0z=a0w=a1x=a1y=a1z=a1w=a2x=a2y=a2z=a2w=0.f;
        const int* hid = header_ids + ((b << 5) + ci) * L_;
        for (int l = 0; l < hlen; ++l) {
            const float* r = word_emb + (size_t)hid[l] * H_ + h;
            float4 v0 = *reinterpret_cast<const float4*>(r);
            float4 v1 = *reinterpret_cast<const float4*>(r + 256);
            float4 v2 = *reinterpret_cast<const float4*>(r + 512);
            a0x+=v0.x; a0y+=v0.y; a0z+=v0.z; a0w+=v0.w;
            a1x+=v1.x; a1y+=v1.y; a1z+=v1.z; a1w+=v1.w;
            a2x+=v2.x; a2y+=v2.y; a2z+=v2.z; a2w+=v2.w;
        }
        const float inv = 1.0f / (float)hlen;
        a0x*=inv; a0y*=inv; a0z*=inv; a0w*=inv;
        a1x*=inv; a1y*=inv; a1z*=inv; a1w*=inv;
        a2x*=inv; a2y*=inv; a2z*=inv; a2w*=inv;
    } else {
        const float* r = word_emb + (size_t)input_ids[tok] * H_ + h;
        float4 v0 = *reinterpret_cast<const float4*>(r);
        float4 v1 = *reinterpret_cast<const float4*>(r + 256);
        float4 v2 = *reinterpret_cast<const float4*>(r + 512);
        a0x=v0.x; a0y=v0.y; a0z=v0.z; a0w=v0.w;
        a1x=v1.x; a1y=v1.y; a1z=v1.z; a1w=v1.w;
        a2x=v2.x; a2y=v2.y; a2z=v2.z; a2w=v2.w;
    }

    // ---- add the four auxiliary embeddings (all loads independent -> deep ILP)
    {
        const float* r = pos_emb + s * H_ + h;
        float4 v0 = *reinterpret_cast<const float4*>(r);
        float4 v1 = *reinterpret_cast<const float4*>(r + 256);
        float4 v2 = *reinterpret_cast<const float4*>(r + 512);
        a0x+=v0.x; a0y+=v0.y; a0z+=v0.z; a0w+=v0.w;
        a1x+=v1.x; a1y+=v1.y; a1z+=v1.z; a1w+=v1.w;
        a2x+=v2.x; a2y+=v2.y; a2z+=v2.z; a2w+=v2.w;
    }
    {
        const float* r = tok_type_emb + token_type_ids[tok] * H_ + h;
        float4 v0 = *reinterpret_cast<const float4*>(r);
        float4 v1 = *reinterpret_cast<const float4*>(r + 256);
        float4 v2 = *reinterpret_cast<const float4*>(r + 512);
        a0x+=v0.x; a0y+=v0.y; a0z+=v0.z; a0w+=v0.w;
        a1x+=v1.x; a1y+=v1.y; a1z+=v1.z; a1w+=v1.w;
        a2x+=v2.x; a2y+=v2.y; a2z+=v2.z; a2w+=v2.w;
    }
    {
        const float* r = match_emb + match_type_ids[tok] * H_ + h;
        float4 v0 = *reinterpret_cast<const float4*>(r);
        float4 v1 = *reinterpret_cast<const float4*>(r + 256);
        float4 v2 = *reinterpret_cast<const float4*>(r + 512);
        a0x+=v0.x; a0y+=v0.y; a0z+=v0.z; a0w+=v0.w;
        a1x+=v1.x; a1y+=v1.y; a1z+=v1.z; a1w+=v1.w;
        a2x+=v2.x; a2y+=v2.y; a2z+=v2.z; a2w+=v2.w;
    }
    {
        const float* r = type_emb + type_idx[tok] * H_ + h;
        float4 v0 = *reinterpret_cast<const float4*>(r);
        float4 v1 = *reinterpret_cast<const float4*>(r + 256);
        float4 v2 = *reinterpret_cast<const float4*>(r + 512);
        a0x+=v0.x; a0y+=v0.y; a0z+=v0.z; a0w+=v0.w;
        a1x+=v1.x; a1y+=v1.y; a1z+=v1.z; a1w+=v1.w;
        a2x+=v2.x; a2y+=v2.y; a2z+=v2.z; a2w+=v2.w;
    }

    // ---- LayerNorm over H=768: wave-level butterfly (all lanes end with totals)
    float s1 = a0x+a0y+a0z+a0w + a1x+a1y+a1z+a1w + a2x+a2y+a2z+a2w;
    float s2 = a0x*a0x+a0y*a0y+a0z*a0z+a0w*a0w
             + a1x*a1x+a1y*a1y+a1z*a1z+a1w*a1w
             + a2x*a2x+a2y*a2y+a2z*a2z+a2w*a2w;
    #pragma unroll
    for (int off = 32; off > 0; off >>= 1) {
        s1 += __shfl_xor(s1, off);
        s2 += __shfl_xor(s2, off);
    }
    const float mean = s1 * (1.0f / H_);
    float var = s2 * (1.0f / H_) - mean * mean;
    var = fmaxf(var, 0.0f);
    const float rstd = rsqrtf(var + 1e-12f);

    // ---- scale/shift, store f32 (3 coalesced 1 KiB stores per wave)
    const float* wp = ln_w + h;
    const float* bp = ln_b + h;
    float* op = out + (size_t)tok * H_ + h;
    {
        float4 w = *reinterpret_cast<const float4*>(wp);
        float4 c = *reinterpret_cast<const float4*>(bp);
        float4 o;
        o.x=(a0x-mean)*rstd*w.x+c.x; o.y=(a0y-mean)*rstd*w.y+c.y;
        o.z=(a0z-mean)*rstd*w.z+c.z; o.w=(a0w-mean)*rstd*w.w+c.w;
        *reinterpret_cast<float4*>(op) = o;
    }
    {
        float4 w = *reinterpret_cast<const float4*>(wp + 256);
        float4 c = *reinterpret_cast<const float4*>(bp + 256);
        float4 o;
        o.x=(a1x-mean)*rstd*w.x+c.x; o.y=(a1y-mean)*rstd*w.y+c.y;
        o.z=(a1z-mean)*rstd*w.z+c.z; o.w=(a1w-mean)*rstd*w.w+c.w;
        *reinterpret_cast<float4*>(op + 256) = o;
    }
    {
        float4 w = *reinterpret_cast<const float4*>(wp + 512);
        float4 c = *reinterpret_cast<const float4*>(bp + 512);
        float4 o;
        o.x=(a2x-mean)*rstd*w.x+c.x; o.y=(a2y-mean)*rstd*w.y+c.y;
        o.z=(a2z-mean)*rstd*w.z+c.z; o.w=(a2w-mean)*rstd*w.w+c.w;
        *reinterpret_cast<float4*>(op + 512) = o;
    }
}

extern "C" void kernel_launch(void* const* d_in, const int* in_sizes, int n_in,
                              void* d_out, int out_size, void* d_ws, size_t ws_size,
                              hipStream_t stream) {
    const int* input_ids      = (const int*)d_in[0];
    const int* header_ids     = (const int*)d_in[1];
    const int* token_type_ids = (const int*)d_in[2];
    const int* match_type_ids = (const int*)d_in[3];
    const int* type_idx       = (const int*)d_in[4];
    const int* col_pos        = (const int*)d_in[5];
    const int* col_idx        = (const int*)d_in[6];
    const int* header_len     = (const int*)d_in[7];
    const float* word_emb     = (const float*)d_in[8];
    const float* pos_emb      = (const float*)d_in[9];
    const float* tok_type_emb = (const float*)d_in[10];
    const float* match_emb    = (const float*)d_in[11];
    const float* type_emb     = (const float*)d_in[12];
    const float* ln_w         = (const float*)d_in[13];
    const float* ln_b         = (const float*)d_in[14];
    float* out = (float*)d_out;

    bert_emb_kernel<<<(B_ * S_) / 4, 256, 0, stream>>>(
        input_ids, header_ids, token_type_ids, match_type_ids, type_idx,
        col_pos, col_idx, header_len, word_emb, pos_emb, tok_type_emb,
        match_emb, type_emb, ln_w, ln_b, out);
}